// Round 1
// baseline (182.051 us; speedup 1.0000x reference)
//
#include <hip/hip_runtime.h>
#include <math.h>

// Problem constants (from reference)
#define B     512
#define DF    2048
#define DA    312
#define NTHR  320   // 5 waves; threads 0..311 each own one column of W

// ---------------------------------------------------------------------------
// Wave (64-lane) reduction helpers
// ---------------------------------------------------------------------------
__device__ __forceinline__ float wave_max_f(float v) {
  #pragma unroll
  for (int off = 32; off >= 1; off >>= 1)
    v = fmaxf(v, __shfl_down(v, off));
  return v;
}

__device__ __forceinline__ double wave_sum_d(double v) {
  #pragma unroll
  for (int off = 32; off >= 1; off >>= 1)
    v += __shfl_down(v, off);
  return v;
}

// ---------------------------------------------------------------------------
// K1: per-row  S_i = sum_d log_softmax(x_f[i,:] @ W + b)_d
// 2 rows per block. x rows staged in LDS (broadcast reads); thread t owns
// column t (t < 312): W reads are lane-contiguous => coalesced.
// ---------------------------------------------------------------------------
__global__ __launch_bounds__(NTHR) void row_stats_kernel(
    const float* __restrict__ x_f, const float* __restrict__ W,
    const float* __restrict__ b, double* __restrict__ S) {
  __shared__ float  xs[2][DF];      // 16 KB: the two x rows
  __shared__ float  pre[2][NTHR];   // pre-activation values per row
  __shared__ float  red_f[8];
  __shared__ double red_d[16];
  __shared__ float  bcast_max;

  const int tid  = threadIdx.x;
  const int wid  = tid >> 6;
  const int lane = tid & 63;
  const int row0 = blockIdx.x * 2;

  // Stage both x rows (contiguous 4096 floats = 1024 float4) into LDS.
  {
    const float4* xrow = (const float4*)(x_f + (size_t)row0 * DF);
    float4* xsv = (float4*)&xs[0][0];
    for (int idx = tid; idx < (2 * DF) / 4; idx += NTHR)
      xsv[idx] = xrow[idx];
  }
  __syncthreads();

  // Dot products: column c = tid; 2 rows; split accumulators for ILP+accuracy.
  const int c = tid;
  if (c < DA) {
    const float* Wc = W + c;
    float s00 = 0.f, s01 = 0.f, s10 = 0.f, s11 = 0.f;
    #pragma unroll 4
    for (int k = 0; k < DF; k += 2) {
      float w0  = Wc[(size_t)(k + 0) * DA];
      float w1  = Wc[(size_t)(k + 1) * DA];
      float x00 = xs[0][k], x01 = xs[0][k + 1];
      float x10 = xs[1][k], x11 = xs[1][k + 1];
      s00 = fmaf(x00, w0, s00);
      s01 = fmaf(x01, w1, s01);
      s10 = fmaf(x10, w0, s10);
      s11 = fmaf(x11, w1, s11);
    }
    float bb = b[c];
    pre[0][c] = (s00 + s01) + bb;
    pre[1][c] = (s10 + s11) + bb;
  }
  __syncthreads();

  // Per-row: max, logsumexp, sum  ->  S = sum_pre - DA*(max + log(sumexp))
  #pragma unroll
  for (int r = 0; r < 2; ++r) {
    float v = (tid < DA) ? pre[r][tid] : -INFINITY;

    // block max
    float m = wave_max_f(v);
    if (lane == 0) red_f[wid] = m;
    __syncthreads();
    if (tid == 0) {
      float mm = red_f[0];
      #pragma unroll
      for (int w = 1; w < NTHR / 64; ++w) mm = fmaxf(mm, red_f[w]);
      bcast_max = mm;
    }
    __syncthreads();
    float rowmax = bcast_max;

    // double-precision sums: exp(v - max) and raw v
    double e  = (tid < DA) ? exp((double)v - (double)rowmax) : 0.0;
    double sp = (tid < DA) ? (double)v : 0.0;
    double es = wave_sum_d(e);
    double ss = wave_sum_d(sp);
    if (lane == 0) { red_d[wid] = es; red_d[8 + wid] = ss; }
    __syncthreads();
    if (tid == 0) {
      double esum = 0.0, ssum = 0.0;
      #pragma unroll
      for (int w = 0; w < NTHR / 64; ++w) { esum += red_d[w]; ssum += red_d[8 + w]; }
      S[row0 + r] = ssum - (double)DA * ((double)rowmax + log(esum));
    }
    __syncthreads();  // protect red_f / bcast_max for next r
  }
}

// ---------------------------------------------------------------------------
// K2: loss = sum_{i<j, lbl_i==lbl_j} (S_j - S_i) / count
// One block, 1024 threads; S and labels cached in LDS.
// ---------------------------------------------------------------------------
__global__ __launch_bounds__(1024) void pair_reduce_kernel(
    const double* __restrict__ S, const int* __restrict__ labels,
    float* __restrict__ out) {
  __shared__ double    Ss[B];
  __shared__ int       Ls[B];
  __shared__ double    red_d[16];
  __shared__ long long red_i[16];

  const int tid = threadIdx.x;
  if (tid < B) { Ss[tid] = S[tid]; Ls[tid] = labels[tid]; }
  __syncthreads();

  double lsum = 0.0;
  long long lcnt = 0;
  for (int p = tid; p < B * B; p += 1024) {
    int i = p >> 9;          // p / 512
    int j = p & (B - 1);     // p % 512
    if (j > i && Ls[i] == Ls[j]) { lsum += Ss[j] - Ss[i]; lcnt++; }
  }

  #pragma unroll
  for (int off = 32; off >= 1; off >>= 1) {
    lsum += __shfl_down(lsum, off);
    lcnt += __shfl_down(lcnt, off);
  }
  const int wid = tid >> 6, lane = tid & 63;
  if (lane == 0) { red_d[wid] = lsum; red_i[wid] = lcnt; }
  __syncthreads();
  if (tid == 0) {
    double s = 0.0; long long c = 0;
    #pragma unroll
    for (int w = 0; w < 16; ++w) { s += red_d[w]; c += red_i[w]; }
    out[0] = (float)((c > 0) ? s / (double)c : s);
  }
}

// ---------------------------------------------------------------------------
extern "C" void kernel_launch(void* const* d_in, const int* in_sizes, int n_in,
                              void* d_out, int out_size, void* d_ws, size_t ws_size,
                              hipStream_t stream) {
  const float* x_f    = (const float*)d_in[0];   // [B, DF]
  const float* W      = (const float*)d_in[1];   // [DF, DA]
  const float* b      = (const float*)d_in[2];   // [DA]
  // d_in[3] = seen_att: mathematically cancels for same-label pairs (unused)
  const int*   labels = (const int*)d_in[4];     // [B] int32

  double* S = (double*)d_ws;                     // 512 doubles = 4 KB scratch

  row_stats_kernel<<<B / 2, NTHR, 0, stream>>>(x_f, W, b, S);
  pair_reduce_kernel<<<1, 1024, 0, stream>>>(S, labels, (float*)d_out);
}

// Round 2
// 116.222 us; speedup vs baseline: 1.5664x; 1.5664x over previous
//
#include <hip/hip_runtime.h>
#include <math.h>

// Problem constants (from reference)
#define B     512
#define DF    2048
#define DA    312
#define NTHR  320   // 5 waves; threads 0..311 each own one column
#define RT    8     // rows per block tile in the GEMM
#define SUB   256   // k sub-chunk staged in LDS

// ---------------------------------------------------------------------------
// Wave (64-lane) reduction helpers
// ---------------------------------------------------------------------------
__device__ __forceinline__ float wave_max_f(float v) {
  #pragma unroll
  for (int off = 32; off >= 1; off >>= 1)
    v = fmaxf(v, __shfl_down(v, off));
  return v;
}

__device__ __forceinline__ double wave_sum_d(double v) {
  #pragma unroll
  for (int off = 32; off >= 1; off >>= 1)
    v += __shfl_down(v, off);
  return v;
}

// ---------------------------------------------------------------------------
// K1: split-K GEMM partials.
// Block (bx, by) computes part[by][row0..row0+RT)[c] = sum over k-chunk
//   x_f[row, k] * W[k, c]   for k in [by*KC, (by+1)*KC).
// Thread c owns one output column: W reads lane-contiguous (coalesced).
// x tile staged in LDS, read back as broadcast float4 (conflict-free).
// 8-way k-unroll => 8 independent W dword loads in flight per wave,
// 64 FMAs per 8 loads (8 rows x 8 k).
// ---------------------------------------------------------------------------
__global__ __launch_bounds__(NTHR) void gemm_partial_kernel(
    const float* __restrict__ x_f, const float* __restrict__ W,
    float* __restrict__ part, int KC) {
  __shared__ float xs[RT][SUB];   // 8 KB

  const int tid  = threadIdx.x;
  const int row0 = blockIdx.x * RT;
  const int k0   = blockIdx.y * KC;
  const int c    = tid;

  float acc[RT];
  #pragma unroll
  for (int r = 0; r < RT; ++r) acc[r] = 0.f;

  for (int ks = 0; ks < KC; ks += SUB) {
    const int kbase = k0 + ks;
    // Stage RT x SUB floats (512 float4 by 320 threads)
    for (int idx = tid; idx < RT * SUB / 4; idx += NTHR) {
      int r  = idx / (SUB / 4);
      int kv = idx - r * (SUB / 4);
      ((float4*)&xs[r][0])[kv] =
          *(const float4*)(x_f + (size_t)(row0 + r) * DF + kbase + kv * 4);
    }
    __syncthreads();

    if (c < DA) {
      const float* Wp = W + (size_t)kbase * DA + c;
      for (int k = 0; k < SUB; k += 8) {
        float w[8];
        #pragma unroll
        for (int j = 0; j < 8; ++j) w[j] = Wp[(size_t)j * DA];
        Wp += (size_t)8 * DA;
        #pragma unroll
        for (int r = 0; r < RT; ++r) {
          const float4 xa = *(const float4*)&xs[r][k];
          const float4 xb = *(const float4*)&xs[r][k + 4];
          acc[r] = fmaf(xa.x, w[0], acc[r]);
          acc[r] = fmaf(xa.y, w[1], acc[r]);
          acc[r] = fmaf(xa.z, w[2], acc[r]);
          acc[r] = fmaf(xa.w, w[3], acc[r]);
          acc[r] = fmaf(xb.x, w[4], acc[r]);
          acc[r] = fmaf(xb.y, w[5], acc[r]);
          acc[r] = fmaf(xb.z, w[6], acc[r]);
          acc[r] = fmaf(xb.w, w[7], acc[r]);
        }
      }
    }
    __syncthreads();
  }

  if (c < DA) {
    #pragma unroll
    for (int r = 0; r < RT; ++r)
      part[((size_t)blockIdx.y * B + row0 + r) * DA + c] = acc[r];
  }
}

// ---------------------------------------------------------------------------
// K2: per-row reduce partials + bias, then
//     S_i = sum_d pre - DA*(max + log(sum exp(pre-max)))   (double accum)
// One block per row, 320 threads, thread c owns column c.
// ---------------------------------------------------------------------------
__global__ __launch_bounds__(NTHR) void row_stats_kernel(
    const float* __restrict__ part, const float* __restrict__ b,
    double* __restrict__ S, int ksplit) {
  __shared__ float  red_f[8];
  __shared__ double red_d[16];
  __shared__ float  bcast_max;

  const int tid  = threadIdx.x;
  const int wid  = tid >> 6;
  const int lane = tid & 63;
  const int row  = blockIdx.x;

  float v = -INFINITY;
  if (tid < DA) {
    float s = b[tid];
    for (int p = 0; p < ksplit; ++p)
      s += part[((size_t)p * B + row) * DA + tid];
    v = s;
  }

  // block max
  float m = wave_max_f(v);
  if (lane == 0) red_f[wid] = m;
  __syncthreads();
  if (tid == 0) {
    float mm = red_f[0];
    #pragma unroll
    for (int w = 1; w < NTHR / 64; ++w) mm = fmaxf(mm, red_f[w]);
    bcast_max = mm;
  }
  __syncthreads();
  const float rowmax = bcast_max;

  // double-precision sums: exp(v - max) and raw v
  double e  = (tid < DA) ? exp((double)v - (double)rowmax) : 0.0;
  double sp = (tid < DA) ? (double)v : 0.0;
  double es = wave_sum_d(e);
  double ss = wave_sum_d(sp);
  if (lane == 0) { red_d[wid] = es; red_d[8 + wid] = ss; }
  __syncthreads();
  if (tid == 0) {
    double esum = 0.0, ssum = 0.0;
    #pragma unroll
    for (int w = 0; w < NTHR / 64; ++w) { esum += red_d[w]; ssum += red_d[8 + w]; }
    S[row] = ssum - (double)DA * ((double)rowmax + log(esum));
  }
}

// ---------------------------------------------------------------------------
// K3: loss = sum_{i<j, lbl_i==lbl_j} (S_j - S_i) / count
// One block, 1024 threads; S and labels cached in LDS.
// ---------------------------------------------------------------------------
__global__ __launch_bounds__(1024) void pair_reduce_kernel(
    const double* __restrict__ S, const int* __restrict__ labels,
    float* __restrict__ out) {
  __shared__ double    Ss[B];
  __shared__ int       Ls[B];
  __shared__ double    red_d[16];
  __shared__ long long red_i[16];

  const int tid = threadIdx.x;
  if (tid < B) { Ss[tid] = S[tid]; Ls[tid] = labels[tid]; }
  __syncthreads();

  double lsum = 0.0;
  long long lcnt = 0;
  for (int p = tid; p < B * B; p += 1024) {
    int i = p >> 9;          // p / 512
    int j = p & (B - 1);     // p % 512
    if (j > i && Ls[i] == Ls[j]) { lsum += Ss[j] - Ss[i]; lcnt++; }
  }

  #pragma unroll
  for (int off = 32; off >= 1; off >>= 1) {
    lsum += __shfl_down(lsum, off);
    lcnt += __shfl_down(lcnt, off);
  }
  const int wid = tid >> 6, lane = tid & 63;
  if (lane == 0) { red_d[wid] = lsum; red_i[wid] = lcnt; }
  __syncthreads();
  if (tid == 0) {
    double s = 0.0; long long c = 0;
    #pragma unroll
    for (int w = 0; w < 16; ++w) { s += red_d[w]; c += red_i[w]; }
    out[0] = (float)((c > 0) ? s / (double)c : s);
  }
}

// ---------------------------------------------------------------------------
extern "C" void kernel_launch(void* const* d_in, const int* in_sizes, int n_in,
                              void* d_out, int out_size, void* d_ws, size_t ws_size,
                              hipStream_t stream) {
  const float* x_f    = (const float*)d_in[0];   // [B, DF]
  const float* W      = (const float*)d_in[1];   // [DF, DA]
  const float* b      = (const float*)d_in[2];   // [DA]
  // d_in[3] = seen_att: cancels exactly for same-label pairs (unused)
  const int*   labels = (const int*)d_in[4];     // [B]

  // ws layout: [ part: ksplit*B*DA floats ][ S: B doubles ]
  int ksplit;
  if (ws_size >= (size_t)8 * B * DA * 4 + 8192) ksplit = 8;
  else                                          ksplit = 1;  // 644 KB fallback

  float*  part = (float*)d_ws;
  size_t  part_bytes = ((size_t)ksplit * B * DA * 4 + 255) & ~(size_t)255;
  double* S    = (double*)((char*)d_ws + part_bytes);
  const int KC = DF / ksplit;

  dim3 g1(B / RT, ksplit);
  gemm_partial_kernel<<<g1, NTHR, 0, stream>>>(x_f, W, part, KC);
  row_stats_kernel<<<B, NTHR, 0, stream>>>(part, b, S, ksplit);
  pair_reduce_kernel<<<1, 1024, 0, stream>>>(S, labels, (float*)d_out);
}

// Round 3
// 112.594 us; speedup vs baseline: 1.6169x; 1.0322x over previous
//
#include <hip/hip_runtime.h>
#include <math.h>

// Problem constants (from reference)
#define B      512
#define DF     2048
#define DA     312
#define NTHR   320   // 5 waves; threads 0..311 each own one output column
#define RT     8     // rows per block tile in the GEMM
#define KSPLIT 16    // k-split factor (grid.y)

// ---------------------------------------------------------------------------
// Wave (64-lane) reduction helpers
// ---------------------------------------------------------------------------
__device__ __forceinline__ float wave_max_f(float v) {
  #pragma unroll
  for (int off = 32; off >= 1; off >>= 1)
    v = fmaxf(v, __shfl_down(v, off));
  return v;
}

__device__ __forceinline__ double wave_sum_d(double v) {
  #pragma unroll
  for (int off = 32; off >= 1; off >>= 1)
    v += __shfl_down(v, off);
  return v;
}

// ---------------------------------------------------------------------------
// K1: split-K GEMM partials, NO LDS.
// Block (bx, by): rows bx*RT..+RT, k-chunk [by*KC, (by+1)*KC).
// Thread c owns one output column: W reads lane-contiguous (coalesced dword).
// x values are wave-uniform -> compiler emits scalar s_load_dwordx8; the FMA
// is v_fmac_f32 vacc, s_x, v_w (one SGPR operand, legal). 8 W loads + 8
// s_loads in flight per 64 FMAs; 1024 blocks -> 4 blocks/CU, 20 waves/CU.
// ---------------------------------------------------------------------------
__global__ __launch_bounds__(NTHR) void gemm_partial_kernel(
    const float* __restrict__ x_f, const float* __restrict__ W,
    float* __restrict__ part, int KC) {
  const int c    = threadIdx.x;
  const int row0 = blockIdx.x * RT;
  const int k0   = blockIdx.y * KC;

  if (c >= DA) return;

  float acc[RT];
  #pragma unroll
  for (int r = 0; r < RT; ++r) acc[r] = 0.f;

  const float* Wp = W + (size_t)k0 * DA + c;
  const float* xp = x_f + (size_t)row0 * DF + k0;

  for (int k = 0; k < KC; k += 8) {
    float w[8];
    #pragma unroll
    for (int j = 0; j < 8; ++j) w[j] = Wp[(size_t)(k + j) * DA];
    #pragma unroll
    for (int r = 0; r < RT; ++r) {
      const float* xr = xp + (size_t)r * DF + k;  // wave-uniform -> s_load
      #pragma unroll
      for (int j = 0; j < 8; ++j) acc[r] = fmaf(xr[j], w[j], acc[r]);
    }
  }

  #pragma unroll
  for (int r = 0; r < RT; ++r)
    part[((size_t)blockIdx.y * B + row0 + r) * DA + c] = acc[r];
}

// ---------------------------------------------------------------------------
// K2: per-row reduce partials + bias, then
//     S_i = sum_d pre - DA*(max + log(sum exp(pre-max)))   (double accum)
// One block per row, 320 threads, thread c owns column c.
// ---------------------------------------------------------------------------
__global__ __launch_bounds__(NTHR) void row_stats_kernel(
    const float* __restrict__ part, const float* __restrict__ b,
    double* __restrict__ S, int ksplit) {
  __shared__ float  red_f[8];
  __shared__ double red_d[16];
  __shared__ float  bcast_max;

  const int tid  = threadIdx.x;
  const int wid  = tid >> 6;
  const int lane = tid & 63;
  const int row  = blockIdx.x;

  float v = -INFINITY;
  if (tid < DA) {
    float s = b[tid];
    for (int p = 0; p < ksplit; ++p)
      s += part[((size_t)p * B + row) * DA + tid];
    v = s;
  }

  // block max
  float m = wave_max_f(v);
  if (lane == 0) red_f[wid] = m;
  __syncthreads();
  if (tid == 0) {
    float mm = red_f[0];
    #pragma unroll
    for (int w = 1; w < NTHR / 64; ++w) mm = fmaxf(mm, red_f[w]);
    bcast_max = mm;
  }
  __syncthreads();
  const float rowmax = bcast_max;

  // double-precision sums: exp(v - max) and raw v
  double e  = (tid < DA) ? exp((double)v - (double)rowmax) : 0.0;
  double sp = (tid < DA) ? (double)v : 0.0;
  double es = wave_sum_d(e);
  double ss = wave_sum_d(sp);
  if (lane == 0) { red_d[wid] = es; red_d[8 + wid] = ss; }
  __syncthreads();
  if (tid == 0) {
    double esum = 0.0, ssum = 0.0;
    #pragma unroll
    for (int w = 0; w < NTHR / 64; ++w) { esum += red_d[w]; ssum += red_d[8 + w]; }
    S[row] = ssum - (double)DA * ((double)rowmax + log(esum));
  }
}

// ---------------------------------------------------------------------------
// K3: loss = sum_{i<j, lbl_i==lbl_j} (S_j - S_i) / count
// One block, 1024 threads; S and labels cached in LDS. Exact (double).
// ---------------------------------------------------------------------------
__global__ __launch_bounds__(1024) void pair_reduce_kernel(
    const double* __restrict__ S, const int* __restrict__ labels,
    float* __restrict__ out) {
  __shared__ double    Ss[B];
  __shared__ int       Ls[B];
  __shared__ double    red_d[16];
  __shared__ long long red_i[16];

  const int tid = threadIdx.x;
  if (tid < B) { Ss[tid] = S[tid]; Ls[tid] = labels[tid]; }
  __syncthreads();

  double lsum = 0.0;
  long long lcnt = 0;
  for (int p = tid; p < B * B; p += 1024) {
    int i = p >> 9;          // p / 512
    int j = p & (B - 1);     // p % 512
    if (j > i && Ls[i] == Ls[j]) { lsum += Ss[j] - Ss[i]; lcnt++; }
  }

  #pragma unroll
  for (int off = 32; off >= 1; off >>= 1) {
    lsum += __shfl_down(lsum, off);
    lcnt += __shfl_down(lcnt, off);
  }
  const int wid = tid >> 6, lane = tid & 63;
  if (lane == 0) { red_d[wid] = lsum; red_i[wid] = lcnt; }
  __syncthreads();
  if (tid == 0) {
    double s = 0.0; long long c = 0;
    #pragma unroll
    for (int w = 0; w < 16; ++w) { s += red_d[w]; c += red_i[w]; }
    out[0] = (float)((c > 0) ? s / (double)c : s);
  }
}

// ---------------------------------------------------------------------------
extern "C" void kernel_launch(void* const* d_in, const int* in_sizes, int n_in,
                              void* d_out, int out_size, void* d_ws, size_t ws_size,
                              hipStream_t stream) {
  const float* x_f    = (const float*)d_in[0];   // [B, DF]
  const float* W      = (const float*)d_in[1];   // [DF, DA]
  const float* b      = (const float*)d_in[2];   // [DA]
  // d_in[3] = seen_att: cancels exactly for same-label pairs (unused)
  const int*   labels = (const int*)d_in[4];     // [B]

  // ws layout: [ part: ksplit*B*DA floats ][ S: B doubles ]
  int ksplit = KSPLIT;
  if (ws_size < (size_t)KSPLIT * B * DA * 4 + 8192) ksplit = 2;  // tiny-ws fallback

  float*  part = (float*)d_ws;
  size_t  part_bytes = ((size_t)ksplit * B * DA * 4 + 255) & ~(size_t)255;
  double* S    = (double*)((char*)d_ws + part_bytes);
  const int KC = DF / ksplit;

  dim3 g1(B / RT, ksplit);
  gemm_partial_kernel<<<g1, NTHR, 0, stream>>>(x_f, W, part, KC);
  row_stats_kernel<<<B, NTHR, 0, stream>>>(part, b, S, ksplit);
  pair_reduce_kernel<<<1, 1024, 0, stream>>>(S, labels, (float*)d_out);
}